// Round 2
// baseline (249.753 us; speedup 1.0000x reference)
//
#include <hip/hip_runtime.h>
#include <math.h>

#define OCT_EPS 1e-8f

typedef float v2f __attribute__((ext_vector_type(2)));
typedef int   v2i __attribute__((ext_vector_type(2)));

__device__ __forceinline__ v2f splat(float s) { v2f v; v.x = s; v.y = s; return v; }
__device__ __forceinline__ v2i splati(int s)  { v2i v; v.x = s; v.y = s; return v; }
__device__ __forceinline__ v2f vfma(v2f a, v2f b, v2f c) {
    return __builtin_elementwise_fma(a, b, c);
}

// Packed A&S 7.1.26 erf-based exact GELU, |erf err| <= 1.5e-7.
// fma/mul lower to v_pk_fma_f32 / v_pk_mul_f32; exp+rcp stay scalar (quarter-rate).
__device__ __forceinline__ v2f gelu2(v2f x) {
    v2i xi   = __builtin_bit_cast(v2i, x);
    v2i sign = xi & splati(0x80000000);
    v2f ax   = __builtin_bit_cast(v2f, xi ^ sign);        // |x|
    v2f z    = ax * splat(0.70710678118654752f);          // |x|/sqrt(2)
    v2f den  = vfma(z, splat(0.3275911f), splat(1.0f));
    v2f t;
    t.x = __builtin_amdgcn_rcpf(den.x);
    t.y = __builtin_amdgcn_rcpf(den.y);
    v2f p = vfma(splat(1.061405429f), t, splat(-1.453152027f));
    p = vfma(p, t, splat(1.421413741f));
    p = vfma(p, t, splat(-0.284496736f));
    p = vfma(p, t, splat(0.254829592f));
    p = p * t;
    v2f nz2 = -(z * z);
    v2f e;
    e.x = __expf(nz2.x);
    e.y = __expf(nz2.y);
    v2f erf_abs = vfma(-p, e, splat(1.0f));               // erf(|x|/sqrt2) in [0,1)
    v2f er = __builtin_bit_cast(v2f, __builtin_bit_cast(v2i, erf_abs) | sign);
    v2f hx = splat(0.5f) * x;
    return vfma(hx, er, hx);                              // 0.5x(1+erf)
}

__global__ __launch_bounds__(256) void g2_ffn_kernel(
    const float* __restrict__ o,
    const float* __restrict__ W1,   // (32,2) row-major
    const float* __restrict__ b1,   // (32,)
    const float* __restrict__ W2,   // (3,32) row-major
    const float* __restrict__ b2,   // (3,)
    const float* __restrict__ alpha_p,
    float* __restrict__ out,
    int n_oct, int half)
{
    int i = blockIdx.x * blockDim.x + threadIdx.x;
    if (i >= half) return;

    size_t i0 = (size_t)i;           // octonion index A
    size_t i1 = (size_t)i + half;    // octonion index B
    bool has1 = (i1 < (size_t)n_oct);

    const float4* ip = (const float4*)o;
    float4 aLo = ip[2 * i0];
    float4 aHi = ip[2 * i0 + 1];
    float4 bLo = has1 ? ip[2 * i1]     : aLo;
    float4 bHi = has1 ? ip[2 * i1 + 1] : aHi;

    // pack: lane-pair (A,B)
    v2f w;  w.x  = aLo.x; w.y  = bLo.x;
    v2f c1; c1.x = aLo.y; c1.y = bLo.y;
    v2f c2; c2.x = aLo.z; c2.y = bLo.z;
    v2f c3; c3.x = aLo.w; c3.y = bLo.w;
    v2f c4; c4.x = aHi.x; c4.y = bHi.x;
    v2f c5; c5.x = aHi.y; c5.y = bHi.y;
    v2f c6; c6.x = aHi.z; c6.y = bHi.z;
    v2f c7; c7.x = aHi.w; c7.y = bHi.w;

    v2f n2 = c1 * c1;
    n2 = vfma(c2, c2, n2);
    n2 = vfma(c3, c3, n2);
    n2 = vfma(c4, c4, n2);
    n2 = vfma(c5, c5, n2);
    n2 = vfma(c6, c6, n2);
    n2 = vfma(c7, c7, n2);
    v2f n;
    n.x = __builtin_amdgcn_sqrtf(n2.x);
    n.y = __builtin_amdgcn_sqrtf(n2.y);
    v2f s = vfma(w, w, n2);          // |o|^2

    // MLP: 2 -> 32 (exact gelu) -> 3, packed over the octonion pair
    v2f a_acc = splat(b2[0]);
    v2f b_acc = splat(b2[1]);
    v2f c_acc = splat(b2[2]);
#pragma unroll
    for (int j = 0; j < 32; ++j) {
        v2f pre = vfma(splat(W1[2 * j]), w,
                  vfma(splat(W1[2 * j + 1]), n, splat(b1[j])));
        v2f h = gelu2(pre);
        a_acc = vfma(splat(W2[j]),      h, a_acc);
        b_acc = vfma(splat(W2[32 + j]), h, b_acc);
        c_acc = vfma(splat(W2[64 + j]), h, c_acc);
    }

    // octonion algebra collapsed: upd = alpha_c*o + beta_c*e0
    v2f four_w2_s = vfma(splat(4.0f) * w, w, -s);
    v2f alpha_c = vfma(splat(2.0f) * b_acc, w, a_acc) + c_acc * four_w2_s;
    v2f beta_c  = -s * vfma(splat(2.0f) * c_acc, w, b_acc);

    // |upd|^2 = a^2 s + 2ab w + b^2
    v2f t2 = vfma(alpha_c * alpha_c, s,
             vfma(splat(2.0f) * alpha_c * beta_c, w, beta_c * beta_c));
    v2f nrm;
    nrm.x = __builtin_amdgcn_sqrtf(t2.x);
    nrm.y = __builtin_amdgcn_sqrtf(t2.y);
    v2f inv;
    inv.x = __builtin_amdgcn_rcpf(fmaxf(nrm.x, OCT_EPS));
    inv.y = __builtin_amdgcn_rcpf(fmaxf(nrm.y, OCT_EPS));

    float alpha_in = alpha_p[0];
    float lam = 1.0f / (1.0f + __expf(-alpha_in));
    v2f vlam = splat(lam);
    v2f oml  = splat(1.0f - lam);

    v2f la = vlam * alpha_c * inv;   // per-component scale
    v2f lb = vlam * beta_c * inv;    // extra on component 0

    v2f r0 = vfma(oml, w,  vfma(la, w,  lb));
    v2f r1 = vfma(oml, c1, la * c1);
    v2f r2 = vfma(oml, c2, la * c2);
    v2f r3 = vfma(oml, c3, la * c3);
    v2f r4 = vfma(oml, c4, la * c4);
    v2f r5 = vfma(oml, c5, la * c5);
    v2f r6 = vfma(oml, c6, la * c6);
    v2f r7 = vfma(oml, c7, la * c7);

    float4* op = (float4*)out;
    float4 oA0 = { r0.x, r1.x, r2.x, r3.x };
    float4 oA1 = { r4.x, r5.x, r6.x, r7.x };
    op[2 * i0]     = oA0;
    op[2 * i0 + 1] = oA1;
    if (has1) {
        float4 oB0 = { r0.y, r1.y, r2.y, r3.y };
        float4 oB1 = { r4.y, r5.y, r6.y, r7.y };
        op[2 * i1]     = oB0;
        op[2 * i1 + 1] = oB1;
    }
}

extern "C" void kernel_launch(void* const* d_in, const int* in_sizes, int n_in,
                              void* d_out, int out_size, void* d_ws, size_t ws_size,
                              hipStream_t stream) {
    const float* o     = (const float*)d_in[0];
    const float* W1    = (const float*)d_in[1];
    const float* b1    = (const float*)d_in[2];
    const float* W2    = (const float*)d_in[3];
    const float* b2    = (const float*)d_in[4];
    const float* alpha = (const float*)d_in[5];
    float* out = (float*)d_out;

    int n_oct = in_sizes[0] / 8;
    int half = (n_oct + 1) / 2;
    int block = 256;
    int grid = (half + block - 1) / block;
    g2_ffn_kernel<<<grid, block, 0, stream>>>(o, W1, b1, W2, b2, alpha, out, n_oct, half);
}